// Round 3
// baseline (86.707 us; speedup 1.0000x reference)
//
#include <hip/hip_runtime.h>
#include <hip/hip_bf16.h>
#include <cstdint>
#include <cstddef>

#define N_NODES 8192
#define IN_DIM  128
#define OUT_DIM 64
#define LRELU_ALPHA 0.2f
#define S_SLICES 4
#define LOG2E 1.44269504f

using f32x16 = __attribute__((ext_vector_type(16))) float;
using bf16x8 = __attribute__((ext_vector_type(8))) short;

typedef const __attribute__((address_space(1))) int* gas_ptr;
typedef __attribute__((address_space(3))) int* las_ptr;

static __device__ __forceinline__ unsigned short f2bf(float x) {
    union { float f; unsigned u; } v; v.f = x;
    unsigned r = v.u + 0x7FFFu + ((v.u >> 16) & 1u);  // RNE (prep only)
    return (unsigned short)(r >> 16);
}

// ---------------------------------------------------------------------------
// K1: h = x@W ; svec = (h@a_src)*log2e ; dvec = (h@a_dst)*log2e ;
// hpack = bf16(h) in MFMA-B layout. Grid 1024 x 256thr, k-split over waves.
// ---------------------------------------------------------------------------
__global__ __launch_bounds__(256) void gat_prep(
    const float* __restrict__ x, const float* __restrict__ W,
    const float* __restrict__ a,
    float* __restrict__ svec, float* __restrict__ dvec,
    unsigned short* __restrict__ hpack)
{
    __shared__ float shA[4][8][64];
    const int tid = threadIdx.x;
    const int w   = tid >> 6;
    const int f   = tid & 63;
    const int i0  = blockIdx.x * 8;

    float acc[8];
#pragma unroll
    for (int r = 0; r < 8; ++r) acc[r] = 0.f;

    const int k0 = w * 32;
#pragma unroll 2
    for (int k = k0; k < k0 + 32; k += 4) {
        const float w0 = W[(k + 0) * OUT_DIM + f];
        const float w1 = W[(k + 1) * OUT_DIM + f];
        const float w2 = W[(k + 2) * OUT_DIM + f];
        const float w3 = W[(k + 3) * OUT_DIM + f];
#pragma unroll
        for (int r = 0; r < 8; ++r) {
            const float4 xv = *reinterpret_cast<const float4*>(
                x + (size_t)(i0 + r) * IN_DIM + k);
            acc[r] = fmaf(xv.x, w0, acc[r]);
            acc[r] = fmaf(xv.y, w1, acc[r]);
            acc[r] = fmaf(xv.z, w2, acc[r]);
            acc[r] = fmaf(xv.w, w3, acc[r]);
        }
    }
#pragma unroll
    for (int r = 0; r < 8; ++r) shA[w][r][f] = acc[r];
    __syncthreads();

    if (w == 0) {
        union { unsigned short us[8]; int4 v; } pk;
#pragma unroll
        for (int r = 0; r < 8; ++r) {
            const float hv = shA[0][r][f] + shA[1][r][f] + shA[2][r][f] + shA[3][r][f];
            pk.us[r] = f2bf(hv);
        }
        const int jb    = i0 >> 4;
        const int jhalf = (i0 >> 3) & 1;
        const int fb    = f >> 5;
        const int lidx  = (f & 31) + 32 * jhalf;
        *reinterpret_cast<int4*>(hpack + ((size_t)(jb * 2 + fb) * 64 + lidx) * 8) = pk.v;
    } else if (w == 1) {
        const float asrc = a[f];
#pragma unroll
        for (int r = 0; r < 8; ++r) {
            const float hv = shA[0][r][f] + shA[1][r][f] + shA[2][r][f] + shA[3][r][f];
            float sv = hv * asrc;
#pragma unroll
            for (int off = 32; off >= 1; off >>= 1) sv += __shfl_xor(sv, off);
            if (f == 0) svec[i0 + r] = sv * LOG2E;
        }
    } else if (w == 2) {
        const float adst = a[OUT_DIM + f];
#pragma unroll
        for (int r = 0; r < 8; ++r) {
            const float hv = shA[0][r][f] + shA[1][r][f] + shA[2][r][f] + shA[3][r][f];
            float dv = hv * adst;
#pragma unroll
            for (int off = 32; off >= 1; off >>= 1) dv += __shfl_xor(dv, off);
            if (f == 0) dvec[i0 + r] = dv * LOG2E;
        }
    }
}

// ---------------------------------------------------------------------------
// K2: barrier-free streaming pass over adj. Grid (256 rb, 4 sl) x 256thr.
// Each wave owns 32 rows x 512 j; 16-j wave-private tiles, double-buffered,
// counted vmcnt(4) (never drained to 0 in steady state). Per tile we stage
// adj (2 insts, 64B/row full-sector) + hpack B-frags (2 insts) via
// global_load_lds w=16; dvec slice lives in LDS. The ONLY in-loop vmem ops
// are these staging loads, so inline vmcnt counting is exact.
// ---------------------------------------------------------------------------
__global__ __launch_bounds__(256, 4) void gat_main(
    const int* __restrict__ adj,
    const float* __restrict__ svec, const float* __restrict__ dvec,
    const int* __restrict__ hpk,
    float* __restrict__ pO, float* __restrict__ pDen)
{
    union SH {
        struct {
            int tiles[4][2][1024];   // [wave][buf][0..511 adj | 512..1023 hpack]
            float dvl[2048];         // block's dvec window (wave-private quarters)
        } s;                          // 40 KB
        struct { float red[4][32][64]; float redden[4][32]; } r;  // 32.5 KB
    };
    __shared__ SH sh;

    const int tid = threadIdx.x;
    const int w   = tid >> 6;
    const int l   = tid & 63;
    const int rb  = blockIdx.x;
    const int sl  = blockIdx.y;
    const int row = l & 31;      // A-fragment row
    const int kh  = l >> 5;      // k-half
    const int i0  = rb * 32;
    const int jwv = sl * 2048 + w * 512;     // wave's private j-window

    const float s_i = svec[i0 + row];        // already * log2e
    const int lrow_a = l >> 2;               // staging: row within 16-row inst
    const int ucol_a = l & 3;                // staging: 16B unit within 64B row chunk

    // stage one 16-j tile: adj 32x16 ints (2 insts) + hpack 2KB (2 insts)
    auto stage = [&](int buf, int t) {
        const int jt0 = jwv + t * 16;
        const int jb2 = (jt0 >> 4) * 2;
#pragma unroll
        for (int q = 0; q < 2; ++q) {
            const int r16 = q * 16 + lrow_a;
            const int up  = ucol_a ^ ((r16 >> 1) & 3);        // XOR swizzle (both sides)
            const int* gs = adj + (size_t)(i0 + r16) * N_NODES + jt0 + up * 4;
            __builtin_amdgcn_global_load_lds((gas_ptr)gs,
                (las_ptr)&sh.s.tiles[w][buf][q * 256], 16, 0, 0);
        }
#pragma unroll
        for (int q = 0; q < 2; ++q) {
            const int* gs = hpk + ((size_t)(jb2 + q) * 64 + l) * 4;
            __builtin_amdgcn_global_load_lds((gas_ptr)gs,
                (las_ptr)&sh.s.tiles[w][buf][512 + q * 256], 16, 0, 0);
        }
    };

    // dvec window -> LDS (wave-private 512 floats, 2 insts)
#pragma unroll
    for (int q = 0; q < 2; ++q) {
        const int* gs = (const int*)dvec + jwv + q * 256 + l * 4;
        __builtin_amdgcn_global_load_lds((gas_ptr)gs,
            (las_ptr)((__attribute__((address_space(3))) int*)&sh.s.dvl[w * 512 + q * 256]),
            16, 0, 0);
    }

    f32x16 acc0, acc1;
#pragma unroll
    for (int r = 0; r < 16; ++r) { acc0[r] = 0.f; acc1[r] = 0.f; }
    float den = 0.f;

    stage(0, 0);
    stage(1, 1);

    const int swz = (row >> 1) & 3;
    auto body = [&](int t, bool last) {
        const int buf = t & 1;
        if (last) asm volatile("s_waitcnt vmcnt(0)" ::: "memory");
        else      asm volatile("s_waitcnt vmcnt(4)" ::: "memory");
        __builtin_amdgcn_sched_barrier(0);

        const int* tb = &sh.s.tiles[w][buf][0];
        const int u0 = (2 * kh)     ^ swz;
        const int u1 = (2 * kh + 1) ^ swz;
        const int4 A0 = *reinterpret_cast<const int4*>(&tb[row * 16 + u0 * 4]);
        const int4 A1 = *reinterpret_cast<const int4*>(&tb[row * 16 + u1 * 4]);
        const bf16x8 b0 = *reinterpret_cast<const bf16x8*>(&tb[512 + l * 4]);
        const bf16x8 b1 = *reinterpret_cast<const bf16x8*>(&tb[768 + l * 4]);
        const int dbase = w * 512 + t * 16 + kh * 8;
        const float4 d0 = *reinterpret_cast<const float4*>(&sh.s.dvl[dbase]);
        const float4 d1 = *reinterpret_cast<const float4*>(&sh.s.dvl[dbase + 4]);

        // all LDS reads of this buffer landed in regs -> safe to overwrite
        asm volatile("s_waitcnt lgkmcnt(0)" ::: "memory");
        __builtin_amdgcn_sched_barrier(0);
        if (t + 2 < 32) stage(buf, t + 2);

        const float dd[8] = {d0.x, d0.y, d0.z, d0.w, d1.x, d1.y, d1.z, d1.w};
        const int   ia[8] = {A0.x, A0.y, A0.z, A0.w, A1.x, A1.y, A1.z, A1.w};
        bf16x8 af;
#pragma unroll
        for (int e = 0; e < 8; ++e) {
            float ev = s_i + dd[e];                 // log2-domain logit
            ev = fmaxf(ev, LRELU_ALPHA * ev);       // lrelu (positive scale commutes)
            float pv = __builtin_amdgcn_exp2f(ev);
            pv = (ia[e] > 0) ? pv : 0.f;
            union { float f; unsigned u; } pu; pu.f = pv;
            pu.u &= 0xFFFF0000u;                    // truncate to bf16
            den += pu.f;                            // denominator consistent w/ numerator
            af[e] = (short)(pu.u >> 16);
        }
        acc0 = __builtin_amdgcn_mfma_f32_32x32x16_bf16(af, b0, acc0, 0, 0, 0);
        acc1 = __builtin_amdgcn_mfma_f32_32x32x16_bf16(af, b1, acc1, 0, 0, 0);
    };

    for (int t = 0; t < 31; ++t) body(t, false);
    body(31, true);

    __syncthreads();   // all waves done with tiles -> union becomes red buffer

    // scatter acc via verified C/D layout: col=l&31, row=(r&3)+8*(r>>2)+4*kh
#pragma unroll
    for (int r = 0; r < 16; ++r) {
        const int orow = (r & 3) + 8 * (r >> 2) + 4 * kh;
        sh.r.red[w][orow][row]      = acc0[r];
        sh.r.red[w][orow][32 + row] = acc1[r];
    }
    const float dtot = den + __shfl_xor(den, 32);
    if (l < 32) sh.r.redden[w][l] = dtot;
    __syncthreads();

    float* po = pO + ((size_t)rb * S_SLICES + sl) * 2048;
    const float* rf = &sh.r.red[0][0][0];
    for (int e = tid; e < 2048; e += 256)
        po[e] = rf[e] + rf[2048 + e] + rf[4096 + e] + rf[6144 + e];
    if (tid < 32) {
        pDen[((size_t)rb * S_SLICES + sl) * 32 + tid] =
            sh.r.redden[0][tid] + sh.r.redden[1][tid] +
            sh.r.redden[2][tid] + sh.r.redden[3][tid];
    }
}

// ---------------------------------------------------------------------------
// K3: sum 4 slice partials, normalize, ELU, write fp32 output.
// ---------------------------------------------------------------------------
__global__ __launch_bounds__(256) void gat_final(
    const float* __restrict__ pO, const float* __restrict__ pDen,
    float* __restrict__ out)
{
    const int idx = blockIdx.x * 256 + threadIdx.x;
    const int i = idx >> 6;
    const int f = idx & 63;
    const int rb = i >> 5;
    const int r  = i & 31;
    const float* po = pO + (size_t)rb * S_SLICES * 2048 + r * 64 + f;
    const float v = po[0] + po[2048] + po[4096] + po[6144];
    const float* pd = pDen + (size_t)rb * S_SLICES * 32 + r;
    const float dsum = pd[0] + pd[32] + pd[64] + pd[96];
    const float o = v / dsum;
    out[idx] = (o > 0.f) ? o : expm1f(o);   // jax.nn.elu, alpha=1
}

extern "C" void kernel_launch(void* const* d_in, const int* in_sizes, int n_in,
                              void* d_out, int out_size, void* d_ws, size_t ws_size,
                              hipStream_t stream)
{
    const float* x   = (const float*)d_in[0];
    const int*   adj = (const int*)d_in[1];
    const float* W   = (const float*)d_in[2];
    const float* a   = (const float*)d_in[3];
    float* out = (float*)d_out;

    float* svec = (float*)d_ws;                                  // 8192 f32
    float* dvec = svec + N_NODES;                                // 8192 f32
    unsigned short* hpack = (unsigned short*)(dvec + N_NODES);   // 1 MB bf16
    float* pO = (float*)(hpack + (size_t)N_NODES * OUT_DIM);     // 8 MB
    float* pDen = pO + (size_t)256 * S_SLICES * 2048;            // 128 KB

    gat_prep<<<N_NODES / 8, 256, 0, stream>>>(x, W, a, svec, dvec, hpack);
    gat_main<<<dim3(256, S_SLICES), 256, 0, stream>>>(adj, svec, dvec,
                                                      (const int*)hpack, pO, pDen);
    gat_final<<<(N_NODES * OUT_DIM) / 256, 256, 0, stream>>>(pO, pDen, out);
}

// Round 5
// 70.710 us; speedup vs baseline: 1.2262x; 1.2262x over previous
//
#include <hip/hip_runtime.h>
#include <hip/hip_bf16.h>
#include <cstdint>
#include <cstddef>

#define N_NODES 8192
#define IN_DIM  128
#define OUT_DIM 64
#define LRELU_ALPHA 0.2f
#define S_SLICES 4
#define LOG2E 1.44269504f

using f32x16 = __attribute__((ext_vector_type(16))) float;
using bf16x8 = __attribute__((ext_vector_type(8))) short;

typedef const __attribute__((address_space(1))) int* gas_ptr;
typedef __attribute__((address_space(3))) int* las_ptr;

static __device__ __forceinline__ unsigned short f2bf(float x) {
    union { float f; unsigned u; } v; v.f = x;
    unsigned r = v.u + 0x7FFFu + ((v.u >> 16) & 1u);  // RNE (prep only)
    return (unsigned short)(r >> 16);
}

// ---------------------------------------------------------------------------
// K1: h = x@W ; svec = (h@a_src)*log2e ; dvec = (h@a_dst)*log2e ;
// hpack = bf16(h) in MFMA-B layout. Grid 1024 x 256thr, k-split over waves.
// ---------------------------------------------------------------------------
__global__ __launch_bounds__(256) void gat_prep(
    const float* __restrict__ x, const float* __restrict__ W,
    const float* __restrict__ a,
    float* __restrict__ svec, float* __restrict__ dvec,
    unsigned short* __restrict__ hpack)
{
    __shared__ float shA[4][8][64];
    const int tid = threadIdx.x;
    const int w   = tid >> 6;
    const int f   = tid & 63;
    const int i0  = blockIdx.x * 8;

    float acc[8];
#pragma unroll
    for (int r = 0; r < 8; ++r) acc[r] = 0.f;

    const int k0 = w * 32;
#pragma unroll 2
    for (int k = k0; k < k0 + 32; k += 4) {
        const float w0 = W[(k + 0) * OUT_DIM + f];
        const float w1 = W[(k + 1) * OUT_DIM + f];
        const float w2 = W[(k + 2) * OUT_DIM + f];
        const float w3 = W[(k + 3) * OUT_DIM + f];
#pragma unroll
        for (int r = 0; r < 8; ++r) {
            const float4 xv = *reinterpret_cast<const float4*>(
                x + (size_t)(i0 + r) * IN_DIM + k);
            acc[r] = fmaf(xv.x, w0, acc[r]);
            acc[r] = fmaf(xv.y, w1, acc[r]);
            acc[r] = fmaf(xv.z, w2, acc[r]);
            acc[r] = fmaf(xv.w, w3, acc[r]);
        }
    }
#pragma unroll
    for (int r = 0; r < 8; ++r) shA[w][r][f] = acc[r];
    __syncthreads();

    if (w == 0) {
        union { unsigned short us[8]; int4 v; } pk;
#pragma unroll
        for (int r = 0; r < 8; ++r) {
            const float hv = shA[0][r][f] + shA[1][r][f] + shA[2][r][f] + shA[3][r][f];
            pk.us[r] = f2bf(hv);
        }
        const int jb    = i0 >> 4;
        const int jhalf = (i0 >> 3) & 1;
        const int fb    = f >> 5;
        const int lidx  = (f & 31) + 32 * jhalf;
        *reinterpret_cast<int4*>(hpack + ((size_t)(jb * 2 + fb) * 64 + lidx) * 8) = pk.v;
    } else if (w == 1) {
        const float asrc = a[f];
#pragma unroll
        for (int r = 0; r < 8; ++r) {
            const float hv = shA[0][r][f] + shA[1][r][f] + shA[2][r][f] + shA[3][r][f];
            float sv = hv * asrc;
#pragma unroll
            for (int off = 32; off >= 1; off >>= 1) sv += __shfl_xor(sv, off);
            if (f == 0) svec[i0 + r] = sv * LOG2E;
        }
    } else if (w == 2) {
        const float adst = a[OUT_DIM + f];
#pragma unroll
        for (int r = 0; r < 8; ++r) {
            const float hv = shA[0][r][f] + shA[1][r][f] + shA[2][r][f] + shA[3][r][f];
            float dv = hv * adst;
#pragma unroll
            for (int off = 32; off >= 1; off >>= 1) dv += __shfl_xor(dv, off);
            if (f == 0) dvec[i0 + r] = dv * LOG2E;
        }
    }
}

// ---------------------------------------------------------------------------
// K2: one pass over adj. Round-2 staging (block super-step = 32 rows x 128 j,
// 512B/row contiguous, XOR-swizzled both sides) with counted-vmcnt raw
// barriers. Per super-step:
//   plains -> vmcnt(12) [stage(s) drained; stage(s+1)+plains stay in flight]
//   -> s_barrier [tile visible] -> ds_reads -> lgkmcnt(0) -> s_barrier
//   [all waves' reads landed => overwrite safe] -> stage(s+2) -> compute.
// The VMEM queue never drains to zero (stage(s+2) = 16KB/block always in
// flight across the compute+next-barrier region).
// ---------------------------------------------------------------------------
__global__ __launch_bounds__(256, 4) void gat_main(
    const int* __restrict__ adj,
    const float* __restrict__ svec, const float* __restrict__ dvec,
    const unsigned short* __restrict__ hpack,
    float* __restrict__ pO, float* __restrict__ pDen)
{
    union SH {
        int tiles[2][32 * 128];                                  // 2 x 16KB adj
        struct { float red[4][32][64]; float redden[4][32]; } r; // 32.5KB
    };
    __shared__ SH sh;

    const int tid = threadIdx.x;
    const int w   = tid >> 6;
    const int l   = tid & 63;
    const int rb  = blockIdx.x;
    const int sl  = blockIdx.y;
    const int row = l & 31;      // A-fragment row (query i within block)
    const int kh  = l >> 5;      // k-half
    const int i0  = rb * 32;
    const int jwin = sl * 2048;

    const float s_i = svec[i0 + row];   // already * log2e
    asm volatile("" :: "v"(s_i));        // force completion before staging begins
    const bf16x8* hp = reinterpret_cast<const bf16x8*>(hpack);

    // stage 32 rows x 128 j (16KB): per wave 4 insts, 2 rows x 512B each,
    // 16B-unit column XOR-swizzled on the GLOBAL side (cg = cp ^ (row&7)).
    auto stage = [&](int buf, int ss) {
        const int jt0 = jwin + ss * 128;
#pragma unroll
        for (int q = 0; q < 4; ++q) {
            const int r0   = (w * 4 + q) * 2;
            const int lrow = r0 + (l >> 5);
            const int cp   = l & 31;
            const int cg   = cp ^ (lrow & 7);
            const int* gsrc = adj + (size_t)(i0 + lrow) * N_NODES + jt0 + cg * 4;
            int* ldst = &sh.tiles[buf][r0 * 128];  // wave-uniform base
            __builtin_amdgcn_global_load_lds((gas_ptr)gsrc, (las_ptr)ldst, 16, 0, 0);
        }
    };

    f32x16 acc0, acc1;
#pragma unroll
    for (int r = 0; r < 16; ++r) { acc0[r] = 0.f; acc1[r] = 0.f; }
    float den = 0.f;

    stage(0, 0);
    stage(1, 1);

    const int swz = row & 7;
    for (int s = 0; s < 16; ++s) {
        const int buf = s & 1;
        const int jt0 = jwin + s * 128;
        const int jg  = jt0 + w * 32;     // wave's 32-j subrange this step
        const int jb  = jg >> 4;

        // ---- plain loads (L2-hit) for this step's compute: issue FIRST ----
        const bf16x8 b00 = hp[(jb * 2 + 0) * 64 + l];
        const bf16x8 b01 = hp[(jb * 2 + 1) * 64 + l];
        const bf16x8 b10 = hp[(jb * 2 + 2) * 64 + l];
        const bf16x8 b11 = hp[(jb * 2 + 3) * 64 + l];
        const int j0 = jg + kh * 8;
        const float4 dA0 = *reinterpret_cast<const float4*>(dvec + j0);
        const float4 dA1 = *reinterpret_cast<const float4*>(dvec + j0 + 4);
        const float4 dB0 = *reinterpret_cast<const float4*>(dvec + j0 + 16);
        const float4 dB1 = *reinterpret_cast<const float4*>(dvec + j0 + 20);

        // 12 newest VMEM ops = plains(s)[8] + stage(s+1)[4]  =>  stage(s) done
        asm volatile("s_waitcnt vmcnt(12)" ::: "memory");
        __builtin_amdgcn_s_barrier();     // all waves' stage(s) visible

        // ---- adj reads from LDS (both MFMA steps), un-swizzle on read ----
        const int* tb = &sh.tiles[buf][0];
        const int c00 = w * 8 + kh * 2;
        const int c10 = w * 8 + 4 + kh * 2;
        const int4 A00 = *reinterpret_cast<const int4*>(&tb[row * 128 + ((c00    ) ^ swz) * 4]);
        const int4 A01 = *reinterpret_cast<const int4*>(&tb[row * 128 + ((c00 + 1) ^ swz) * 4]);
        const int4 A10 = *reinterpret_cast<const int4*>(&tb[row * 128 + ((c10    ) ^ swz) * 4]);
        const int4 A11 = *reinterpret_cast<const int4*>(&tb[row * 128 + ((c10 + 1) ^ swz) * 4]);
        asm volatile("s_waitcnt lgkmcnt(0)" ::: "memory");  // reads landed in regs
        __builtin_amdgcn_s_barrier();     // all waves done reading buf

        // overwrite of buf now safe: stage two steps ahead
        if (s + 2 < 16) stage(buf, s + 2);

        // ---- compute (registers only) ----
        const float dd0[8] = {dA0.x, dA0.y, dA0.z, dA0.w, dA1.x, dA1.y, dA1.z, dA1.w};
        const int   ia0[8] = {A00.x, A00.y, A00.z, A00.w, A01.x, A01.y, A01.z, A01.w};
        const float dd1[8] = {dB0.x, dB0.y, dB0.z, dB0.w, dB1.x, dB1.y, dB1.z, dB1.w};
        const int   ia1[8] = {A10.x, A10.y, A10.z, A10.w, A11.x, A11.y, A11.z, A11.w};

        bf16x8 af0, af1;
#pragma unroll
        for (int e = 0; e < 8; ++e) {
            float ev = s_i + dd0[e];
            ev = fmaxf(ev, LRELU_ALPHA * ev);
            float pv = __builtin_amdgcn_exp2f(ev);
            pv = (ia0[e] > 0) ? pv : 0.f;
            union { float f; unsigned u; } pu; pu.f = pv;
            pu.u &= 0xFFFF0000u;
            den += pu.f;
            af0[e] = (short)(pu.u >> 16);
        }
#pragma unroll
        for (int e = 0; e < 8; ++e) {
            float ev = s_i + dd1[e];
            ev = fmaxf(ev, LRELU_ALPHA * ev);
            float pv = __builtin_amdgcn_exp2f(ev);
            pv = (ia1[e] > 0) ? pv : 0.f;
            union { float f; unsigned u; } pu; pu.f = pv;
            pu.u &= 0xFFFF0000u;
            den += pu.f;
            af1[e] = (short)(pu.u >> 16);
        }
        acc0 = __builtin_amdgcn_mfma_f32_32x32x16_bf16(af0, b00, acc0, 0, 0, 0);
        acc1 = __builtin_amdgcn_mfma_f32_32x32x16_bf16(af0, b01, acc1, 0, 0, 0);
        acc0 = __builtin_amdgcn_mfma_f32_32x32x16_bf16(af1, b10, acc0, 0, 0, 0);
        acc1 = __builtin_amdgcn_mfma_f32_32x32x16_bf16(af1, b11, acc1, 0, 0, 0);
    }

    __syncthreads();   // full drain; union becomes the reduction buffer

    // scatter acc via verified C/D layout: col=l&31, row=(r&3)+8*(r>>2)+4*kh
#pragma unroll
    for (int r = 0; r < 16; ++r) {
        const int orow = (r & 3) + 8 * (r >> 2) + 4 * kh;
        sh.r.red[w][orow][row]      = acc0[r];
        sh.r.red[w][orow][32 + row] = acc1[r];
    }
    const float dtot = den + __shfl_xor(den, 32);
    if (l < 32) sh.r.redden[w][l] = dtot;
    __syncthreads();

    float* po = pO + ((size_t)rb * S_SLICES + sl) * 2048;
    const float* rf = &sh.r.red[0][0][0];
    for (int e = tid; e < 2048; e += 256)
        po[e] = rf[e] + rf[2048 + e] + rf[4096 + e] + rf[6144 + e];
    if (tid < 32) {
        pDen[((size_t)rb * S_SLICES + sl) * 32 + tid] =
            sh.r.redden[0][tid] + sh.r.redden[1][tid] +
            sh.r.redden[2][tid] + sh.r.redden[3][tid];
    }
}

// ---------------------------------------------------------------------------
// K3: sum 4 slice partials, normalize, ELU, write fp32 output.
// ---------------------------------------------------------------------------
__global__ __launch_bounds__(256) void gat_final(
    const float* __restrict__ pO, const float* __restrict__ pDen,
    float* __restrict__ out)
{
    const int idx = blockIdx.x * 256 + threadIdx.x;
    const int i = idx >> 6;
    const int f = idx & 63;
    const int rb = i >> 5;
    const int r  = i & 31;
    const float* po = pO + (size_t)rb * S_SLICES * 2048 + r * 64 + f;
    const float v = po[0] + po[2048] + po[4096] + po[6144];
    const float* pd = pDen + (size_t)rb * S_SLICES * 32 + r;
    const float dsum = pd[0] + pd[32] + pd[64] + pd[96];
    const float o = v / dsum;
    out[idx] = (o > 0.f) ? o : expm1f(o);   // jax.nn.elu, alpha=1
}

extern "C" void kernel_launch(void* const* d_in, const int* in_sizes, int n_in,
                              void* d_out, int out_size, void* d_ws, size_t ws_size,
                              hipStream_t stream)
{
    const float* x   = (const float*)d_in[0];
    const int*   adj = (const int*)d_in[1];
    const float* W   = (const float*)d_in[2];
    const float* a   = (const float*)d_in[3];
    float* out = (float*)d_out;

    float* svec = (float*)d_ws;                                  // 8192 f32
    float* dvec = svec + N_NODES;                                // 8192 f32
    unsigned short* hpack = (unsigned short*)(dvec + N_NODES);   // 1 MB bf16
    float* pO = (float*)(hpack + (size_t)N_NODES * OUT_DIM);     // 8 MB
    float* pDen = pO + (size_t)256 * S_SLICES * 2048;            // 128 KB

    gat_prep<<<N_NODES / 8, 256, 0, stream>>>(x, W, a, svec, dvec, hpack);
    gat_main<<<dim3(256, S_SLICES), 256, 0, stream>>>(adj, svec, dvec, hpack, pO, pDen);
    gat_final<<<(N_NODES * OUT_DIM) / 256, 256, 0, stream>>>(pO, pDen, out);
}